// Round 7
// baseline (1159.429 us; speedup 1.0000x reference)
//
#include <hip/hip_runtime.h>
#include <hip/hip_bf16.h>

#define BB 128
#define LL 128
#define DD 300
#define MDIM 50
#define GINDIM 350
#define HDIM 256     // per-direction hidden
#define G3 768       // 3*HDIM
#define HH 512       // ctx dim
#define RR 128
#define TT 4
#define NKB 4        // branches
#define MTOT (BB*LL) // 16384
#define N2 1536      // both dirs stacked gates
#define KP 352       // padded GRU-input K

typedef __attribute__((ext_vector_type(8))) short short8;
typedef __attribute__((ext_vector_type(4))) float f32x4;

// ---------------- ws layout (bytes) ----------------
#define OFF_GI      0ull            // bf16 [2][16384][768] = 50,331,648
#define OFF_CTXB    50331648ull     // bf16 [16384][512] = 16,777,216
#define OFF_WIHB    78643200ull     // bf16 [1536][352]  = 1,081,344
#define OFF_WHHB    79724544ull     // bf16 [2][768][256]= 786,432
#define OFF_BIAS    80510976ull     // f32 [1536]
#define OFF_W2      80517120ull     // f32 [16][512] = 32,768
#define OFF_B2      80549888ull     // f32 [16]
#define OFF_BEG     80550144ull     // int [128]
#define OFF_TN      80550656ull     // int [128]
#define OFF_SCORES  80551168ull     // f32 [128][3]
#define OFF_FK      80553216ull     // f32 [4][16384][4] = 1,048,576
#define OFF_AL      81601792ull     // f32 [4][128][128][4] = 1,048,576
#define OFF_SP      82650368ull     // f32 [4][128][128] = 262,144
#define OFF_SPSUM   82912512ull     // f32 [4][128]
#define OFF_SV      82914560ull     // f32 [128][2048] = 1,048,576

__device__ __forceinline__ float sig_f(float x) { return 1.f / (1.f + __expf(-x)); }
__device__ __forceinline__ float tanh_f(float x) { float e = __expf(2.f * x); return 1.f - 2.f / (e + 1.f); }
__device__ __forceinline__ float b2f(unsigned short u) { return __uint_as_float(((unsigned)u) << 16); }

// ---------------- merged prep: wihB+bias | whhB | W2+b2 | beg/tn ----------------
#define NB_WIH 2112   // 1536*352/256
#define NB_WHH 1536   // 2*768*256/256
#define NB_W2  32     // 16*512/256
__global__ __launch_bounds__(256) void k_prep_all(
        const float* __restrict__ gWihf, const float* __restrict__ gWihb,
        const float* __restrict__ gbihf, const float* __restrict__ gbihb,
        const float* __restrict__ gbhhf, const float* __restrict__ gbhhb,
        const float* __restrict__ gWhhf, const float* __restrict__ gWhhb,
        const float* __restrict__ hW, const float* __restrict__ hb,
        const float* __restrict__ tW, const float* __restrict__ tb,
        const int* __restrict__ masks,
        __hip_bfloat16* __restrict__ wihB, float* __restrict__ biasAll,
        __hip_bfloat16* __restrict__ whhB,
        float* __restrict__ W2, float* __restrict__ b2,
        int* __restrict__ beg, int* __restrict__ tn) {
    const int bid = blockIdx.x;
    const int t = threadIdx.x;
    if (bid < NB_WIH) {
        int idx = bid * 256 + t;
        int n = idx / KP, k = idx % KP;
        int dir = n >= G3; int g = n - dir * G3;
        const float* W = dir ? gWihb : gWihf;
        float v = (k < GINDIM) ? W[(size_t)g * GINDIM + k] : 0.f;
        wihB[idx] = __float2bfloat16(v);
        if (idx < N2) {
            int d2 = idx >= G3; int g2 = idx - d2 * G3;
            float b = d2 ? gbihb[g2] : gbihf[g2];
            if (g2 < 2 * HDIM) b += d2 ? gbhhb[g2] : gbhhf[g2];  // fold r,z hidden bias
            biasAll[idx] = b;
        }
    } else if (bid < NB_WIH + NB_WHH) {
        int idx = (bid - NB_WIH) * 256 + t;
        int dir = idx / (G3 * HDIM);
        const float* W = dir ? gWhhb : gWhhf;
        whhB[idx] = __float2bfloat16(W[idx - dir * G3 * HDIM]);
    } else if (bid < NB_WIH + NB_WHH + NB_W2) {
        int idx = (bid - NB_WIH - NB_WHH) * 256 + t;
        int kt = idx >> 9, h = idx & 511;
        int k = kt >> 2, tt = kt & 3;
        const float* tw = tW + (size_t)(k * TT + tt) * RR;
        const float* hw = hW + (size_t)k * RR * HH + h;
        float acc = 0.f;
        #pragma unroll 4
        for (int r = 0; r < RR; ++r) acc += tw[r] * hw[(size_t)r * HH];
        W2[idx] = acc;
        if (idx < 16) {
            int k2 = idx >> 2, t2 = idx & 3;
            const float* tw2 = tW + (size_t)(k2 * TT + t2) * RR;
            const float* hbk = hb + k2 * RR;
            float a = tb[k2 * TT + t2];
            for (int r = 0; r < RR; ++r) a += tw2[r] * hbk[r];
            b2[idx] = a;
        }
    } else {
        if (t < 128) {
            int b = t;
            int best = masks[b * LL]; int idx = 0; int s = 0;
            for (int j = 0; j < LL; ++j) {
                int v = masks[b * LL + j]; s += v;
                if (v > best) { best = v; idx = j; }
            }
            beg[b] = idx; tn[b] = s;
        }
    }
}

// ---------------- MFMA GEMM 1: gi = x @ Wih^T + bias (x built inline from sents) ----------------
__global__ __launch_bounds__(256) void k_mfma_gi(const float* __restrict__ sents,
        const float* __restrict__ mask_table, const int* __restrict__ masks,
        const short* __restrict__ wihB, const float* __restrict__ biasAll,
        __hip_bfloat16* __restrict__ gi) {
    __shared__ short As[64][40];
    __shared__ short Bs[64][40];
    const int tid = threadIdx.x;
    const int m0 = blockIdx.y * 64, n0 = blockIdx.x * 64;
    const int w = tid >> 6, lane = tid & 63;
    const int srow = tid >> 2, skc = (tid & 3) * 8;
    const int frow = lane & 15, fkc = (lane >> 4) * 8;
    const int rb = (w >> 1) * 32, cb = (w & 1) * 32;
    const int m = m0 + srow;
    const float* sr = sents + (size_t)m * DD;
    const float* mr = mask_table + masks[m] * MDIM;
    f32x4 zero = {0.f, 0.f, 0.f, 0.f};
    f32x4 acc[2][2] = {zero, zero, zero, zero};
    for (int k0 = 0; k0 < KP; k0 += 32) {
        short8 av;
        #pragma unroll
        for (int j = 0; j < 8; ++j) {
            int k = k0 + skc + j;
            float v = (k < DD) ? sr[k] : ((k < GINDIM) ? mr[k - DD] : 0.f);
            __hip_bfloat16 bb = __float2bfloat16(v);
            av[j] = *reinterpret_cast<short*>(&bb);
        }
        *(short8*)&As[srow][skc] = av;
        *(short8*)&Bs[srow][skc] = *(const short8*)&wihB[(size_t)(n0 + srow) * KP + k0 + skc];
        __syncthreads();
        short8 a[2], b[2];
        #pragma unroll
        for (int i = 0; i < 2; ++i) a[i] = *(const short8*)&As[rb + i * 16 + frow][fkc];
        #pragma unroll
        for (int j = 0; j < 2; ++j) b[j] = *(const short8*)&Bs[cb + j * 16 + frow][fkc];
        #pragma unroll
        for (int i = 0; i < 2; ++i)
            #pragma unroll
            for (int j = 0; j < 2; ++j)
                acc[i][j] = __builtin_amdgcn_mfma_f32_16x16x32_bf16(a[i], b[j], acc[i][j], 0, 0, 0);
        __syncthreads();
    }
    #pragma unroll
    for (int i = 0; i < 2; ++i) {
        #pragma unroll
        for (int j = 0; j < 2; ++j) {
            int col = n0 + cb + j * 16 + frow;
            int dir = col >= G3; int g = col - dir * G3;
            float bias = biasAll[col];
            #pragma unroll
            for (int r = 0; r < 4; ++r) {
                int mm = m0 + rb + i * 16 + (lane >> 4) * 4 + r;
                gi[((size_t)dir * MTOT + mm) * G3 + g] = __float2bfloat16(acc[i][j][r] + bias);
            }
        }
    }
}

// ---------------- pos weight ----------------
__device__ __forceinline__ float poswt(int j, int beg, int tn, int len, float lf, int mv) {
    float w = (j < beg) ? (1.f - (float)(beg - j) / lf) : 0.f;
    if (mv == 1) w = 1.f;
    if (j > beg + tn) w = 1.f - (float)(j - beg) / lf;
    if (j > len) w = 0.f;
    return w;
}

// ---------------- GRU recurrence via MFMA: 16 blocks x 1024 threads ----------------
// Wave w owns 48 gate cols (3 col-tiles): 24 B-frags = 96 VGPR, pinned via asm.
#define LB(ct,kk) short8 bu_##ct##_##kk = *(const short8*)(wB + (ct * 16) * HDIM + (kk) * 32);
#define LBCT(ct) LB(ct,0) LB(ct,1) LB(ct,2) LB(ct,3) LB(ct,4) LB(ct,5) LB(ct,6) LB(ct,7)
#define KEEP(ct,kk) asm volatile("" : "+v"(bu_##ct##_##kk));
#define KEEPCT(ct) KEEP(ct,0) KEEP(ct,1) KEEP(ct,2) KEEP(ct,3) KEEP(ct,4) KEEP(ct,5) KEEP(ct,6) KEEP(ct,7)
#define MM(kk) { const short8 a = *(const short8*)(aB + (kk) * 32); \
    acc0 = __builtin_amdgcn_mfma_f32_16x16x32_bf16(a, bu_0_##kk, acc0, 0, 0, 0); \
    acc1 = __builtin_amdgcn_mfma_f32_16x16x32_bf16(a, bu_1_##kk, acc1, 0, 0, 0); \
    acc2 = __builtin_amdgcn_mfma_f32_16x16x32_bf16(a, bu_2_##kk, acc2, 0, 0, 0); }
#define GW(ct,accv) { const int col = colg + ct * 16 + frow; \
    gates[r0 + 0][col] = accv[0]; gates[r0 + 1][col] = accv[1]; \
    gates[r0 + 2][col] = accv[2]; gates[r0 + 3][col] = accv[3]; }
#define PF(q, lenq, r0q, r1q, r2q) { \
    int pos = dir ? (lenq - 1 - l) : l; \
    if (l >= lenq) pos = 0; \
    const short* grow = giD + ((size_t)((b0 + bbase + q) * LL + pos)) * G3 + i_idx; \
    r0q = (unsigned short)grow[0]; r1q = (unsigned short)grow[HDIM]; r2q = (unsigned short)grow[2 * HDIM]; }
#define NQ(q, hvq, lenq, r0q, r1q, r2q) { \
    const int bl = bbase + q; \
    const bool valid = l < lenq; \
    int pos = dir ? (lenq - 1 - l) : l; \
    if (!valid) pos = 0; \
    float rr = sig_f(b2f(r0q) + gates[bl][i_idx]); \
    float zz = sig_f(b2f(r1q) + gates[bl][HDIM + i_idx]); \
    float nn = tanh_f(b2f(r2q) + rr * (gates[bl][2 * HDIM + i_idx] + bhn)); \
    float h = (1.f - zz) * nn + zz * hvq; \
    if (valid) { \
        hvq = h; \
        __hip_bfloat16 hb16 = __float2bfloat16(h); \
        hA[bl][i_idx] = *(short*)&hb16; \
        float hw = h * s_w[bl][pos]; \
        ctxb[((size_t)(b0 + bl) * LL + pos) * HH + dirH + i_idx] = __float2bfloat16(hw); \
    } }

__global__ __launch_bounds__(1024) __attribute__((amdgpu_waves_per_eu(4, 4)))
void k_gru_mfma(
        const short* __restrict__ gi, const short* __restrict__ whhB,
        const float* __restrict__ gbhhf, const float* __restrict__ gbhhb,
        const int* __restrict__ lens, const int* __restrict__ masks,
        const int* __restrict__ beg_, const int* __restrict__ tn_,
        __hip_bfloat16* __restrict__ ctxb) {
    __shared__ float gates[16][772];     // 49,408 B
    __shared__ short hA[16][264];        //  8,448 B
    __shared__ float s_w[16][128];       //  8,192 B
    __shared__ int s_len[16];
    __shared__ int s_maxlen;

    const int tid = threadIdx.x;
    const int w = tid >> 6, lane = tid & 63;
    const int dir = blockIdx.x >> 3, grp = blockIdx.x & 7;
    const int b0 = grp * 16;
    const int frow = lane & 15, fkc = (lane >> 4) * 8;
    const int colg = w * 48;
    const int r0 = (lane >> 4) * 4;
    const int dirH = dir * HDIM;

    if (tid < 16) s_len[tid] = lens[b0 + tid];
    for (int e = tid; e < 16 * 264; e += 1024) ((short*)hA)[e] = 0;
    __syncthreads();
    if (tid == 0) {
        int m = 0;
        #pragma unroll
        for (int q = 0; q < 16; ++q) m = max(m, s_len[q]);
        s_maxlen = m;
    }
    for (int e = tid; e < 16 * 128; e += 1024) {
        int bl = e >> 7, j = e & 127;
        int b = b0 + bl;
        int len = s_len[bl];
        s_w[bl][j] = poswt(j, beg_[b], tn_[b], len, (float)len, masks[b * LL + j]);
    }

    // ---- B fragments: 24 named short8 (96 VGPR), loaded once, pinned ----
    const short* wB = whhB + ((size_t)dir * G3 + colg + frow) * HDIM + fkc;
    LBCT(0) LBCT(1) LBCT(2)
    KEEPCT(0) KEEPCT(1) KEEPCT(2)

    const int i_idx = tid & 255;
    const int bbase = (tid >> 8) * 4;     // 4 batches per thread
    const float bhn = (dir ? gbhhb : gbhhf)[2 * HDIM + i_idx];
    const short* giD = gi + (size_t)dir * MTOT * G3;
    const short* aB = &hA[frow][fkc];
    float hv0 = 0.f, hv1 = 0.f, hv2 = 0.f, hv3 = 0.f;
    __syncthreads();
    const int maxlen = s_maxlen;
    const int len0 = s_len[bbase + 0], len1 = s_len[bbase + 1];
    const int len2 = s_len[bbase + 2], len3 = s_len[bbase + 3];

    const f32x4 zero = {0.f, 0.f, 0.f, 0.f};
    for (int l = 0; l < maxlen; ++l) {
        // ---- prefetch gi for this step into registers ----
        unsigned short p00, p01, p02, p10, p11, p12, p20, p21, p22, p30, p31, p32;
        PF(0, len0, p00, p01, p02)
        PF(1, len1, p10, p11, p12)
        PF(2, len2, p20, p21, p22)
        PF(3, len3, p30, p31, p32)
        // ---- MFMA: gates_pre = h @ Whh^T ----
        f32x4 acc0 = zero, acc1 = zero, acc2 = zero;
        MM(0) MM(1) MM(2) MM(3) MM(4) MM(5) MM(6) MM(7)
        GW(0, acc0) GW(1, acc1) GW(2, acc2)
        __syncthreads();
        // ---- nonlinearity ----
        NQ(0, hv0, len0, p00, p01, p02)
        NQ(1, hv1, len1, p10, p11, p12)
        NQ(2, hv2, len2, p20, p21, p22)
        NQ(3, hv3, len3, p30, p31, p32)
        __syncthreads();
    }
}

// ---------------- fused fk = ctxb @ W2^T + b2 ----------------
__global__ __launch_bounds__(256) void k_fk(const __hip_bfloat16* __restrict__ ctxb,
        const float* __restrict__ W2, const float* __restrict__ b2,
        float* __restrict__ fk) {
    int gid = blockIdx.x * 256 + threadIdx.x;  // MTOT*16
    int m = gid >> 4, kt = gid & 15;
    const short8* crow = (const short8*)((const short*)ctxb + (size_t)m * HH);
    const float* w2 = W2 + kt * HH;
    float acc = b2[kt];
    #pragma unroll 4
    for (int c = 0; c < HH / 8; ++c) {
        short8 v = crow[c];
        #pragma unroll
        for (int j = 0; j < 8; ++j)
            acc += b2f((unsigned short)v[j]) * w2[c * 8 + j];
    }
    fk[((size_t)(kt >> 2) * MTOT + m) * TT + (kt & 3)] = acc;
}

// ---------------- CRF forward/backward marginals (4 lanes per (k,b)) ----------------
__global__ __launch_bounds__(64) void k_crf(const float* __restrict__ fk,
        const float* __restrict__ trans, const int* __restrict__ lens,
        float* __restrict__ alphas, float* __restrict__ sp, float* __restrict__ spsum) {
    const int tid = blockIdx.x * 64 + threadIdx.x;   // 2048 total
    const int pid = tid >> 2;                        // 512 pairs
    const int t = tid & 3;
    const int k = pid >> 7, b = pid & 127;
    const int len = lens[b];
    const float* f = fk + ((size_t)k * MTOT + (size_t)b * LL) * TT;
    const float* tr = trans + k * 16;
    const float trC0 = tr[0 * 4 + t], trC1 = tr[1 * 4 + t], trC2 = tr[2 * 4 + t], trC3 = tr[3 * 4 + t];
    const float trR0 = tr[t * 4 + 0], trR1 = tr[t * 4 + 1], trR2 = tr[t * 4 + 2], trR3 = tr[t * 4 + 3];
    float* al = alphas + ((size_t)k * BB + b) * LL * TT;
    const int base = threadIdx.x & ~3;
    float alpha = f[t];
    al[t] = alpha;
    for (int l = 1; l < LL; ++l) {
        float a0 = __shfl(alpha, base + 0);
        float a1 = __shfl(alpha, base + 1);
        float a2 = __shfl(alpha, base + 2);
        float a3 = __shfl(alpha, base + 3);
        float v0 = a0 + trC0, v1 = a1 + trC1, v2 = a2 + trC2, v3 = a3 + trC3;
        float mx = fmaxf(fmaxf(v0, v1), fmaxf(v2, v3));
        float sum = __expf(v0 - mx) + __expf(v1 - mx) + __expf(v2 - mx) + __expf(v3 - mx);
        float nw = mx + __logf(sum) + f[l * TT + t];
        if (l < len) alpha = nw;
        al[l * TT + t] = alpha;
    }
    float beta = 0.f;
    float ssum = 0.f;
    for (int l = LL - 1; l >= 0; --l) {
        if (l < LL - 1) {
            float fb = f[(l + 1) * TT + t] + beta;
            float c0 = __shfl(fb, base + 0);
            float c1 = __shfl(fb, base + 1);
            float c2 = __shfl(fb, base + 2);
            float c3 = __shfl(fb, base + 3);
            float w0 = trR0 + c0, w1 = trR1 + c1, w2 = trR2 + c2, w3 = trR3 + c3;
            float mx = fmaxf(fmaxf(w0, w1), fmaxf(w2, w3));
            float nb = mx + __logf(__expf(w0 - mx) + __expf(w1 - mx) + __expf(w2 - mx) + __expf(w3 - mx));
            if (l + 1 < len) beta = nb;
        }
        float v = al[l * TT + t] + beta;
        float mx = fmaxf(v, __shfl_xor(v, 1));
        mx = fmaxf(mx, __shfl_xor(mx, 2));
        float p = __expf(v - mx);
        float s = p;
        s += __shfl_xor(s, 1);
        s += __shfl_xor(s, 2);
        float m1 = __shfl(p, base + 1) / s;
        float spv = (l < len) ? m1 : 0.f;
        if (t == 0) sp[((size_t)k * BB + b) * LL + l] = spv;
        ssum += spv;
    }
    if (t == 0) spsum[k * BB + b] = ssum;
}

// ---------------- pooling: sv[b, k*512+h] (bf16 ctx, vectorized) ----------------
__global__ __launch_bounds__(256) void k_pool(const __hip_bfloat16* __restrict__ ctxb,
        const float* __restrict__ sp, const float* __restrict__ spsum,
        float* __restrict__ sv) {
    __shared__ float s_sp[NKB][LL];
    __shared__ float s_inv[NKB];
    const int b = blockIdx.x;
    const int tid = threadIdx.x;
    for (int i = tid; i < NKB * LL; i += 256) {
        int k = i >> 7, l = i & 127;
        s_sp[k][l] = sp[((size_t)k * BB + b) * LL + l];
    }
    if (tid < NKB) s_inv[tid] = 1.f / spsum[tid * BB + b];
    __syncthreads();
    const int n0 = tid * 8;
    const int k = n0 >> 9, h0 = n0 & 511;
    float acc[8] = {};
    const short* cb = (const short*)ctxb;
    for (int l = 0; l < LL; ++l) {
        float spl = s_sp[k][l];
        short8 v = *(const short8*)&cb[((size_t)b * LL + l) * HH + h0];
        #pragma unroll
        for (int j = 0; j < 8; ++j)
            acc[j] += spl * b2f((unsigned short)v[j]);
    }
    float inv = s_inv[k];
    #pragma unroll
    for (int j = 0; j < 8; ++j)
        sv[(size_t)b * 2048 + n0 + j] = acc[j] * inv;
}

// ---------------- scores[b][3] = relu(sv[b]) @ lW^T + lb ----------------
__global__ __launch_bounds__(256) void k_scores(const float* __restrict__ sv,
        const float* __restrict__ lW, const float* __restrict__ lb,
        float* __restrict__ scores) {
    __shared__ float red[3][4];
    const int b = blockIdx.x;
    const int tid = threadIdx.x;
    const float* svb = sv + (size_t)b * 2048;
    float a0 = 0.f, a1 = 0.f, a2 = 0.f;
    for (int i = tid; i < 2048; i += 256) {
        float v = fmaxf(svb[i], 0.f);
        a0 += v * lW[i];
        a1 += v * lW[2048 + i];
        a2 += v * lW[4096 + i];
    }
    #pragma unroll
    for (int off = 32; off > 0; off >>= 1) {
        a0 += __shfl_down(a0, off);
        a1 += __shfl_down(a1, off);
        a2 += __shfl_down(a2, off);
    }
    const int wid = tid >> 6, lane = tid & 63;
    if (lane == 0) { red[0][wid] = a0; red[1][wid] = a1; red[2][wid] = a2; }
    __syncthreads();
    if (tid < 3) {
        scores[b * 3 + tid] = red[tid][0] + red[tid][1] + red[tid][2] + red[tid][3] + lb[tid];
    }
}

// ---------------- final: log-softmax + mean NLL (float32 out) ----------------
__global__ __launch_bounds__(128) void k_final2(const float* __restrict__ scores,
        const int* __restrict__ labels, float* __restrict__ out) {
    __shared__ float red[128];
    const int b = threadIdx.x;
    float s0 = scores[b * 3 + 0], s1 = scores[b * 3 + 1], s2 = scores[b * 3 + 2];
    float mx = fmaxf(s0, fmaxf(s1, s2));
    float lse = mx + logf(expf(s0 - mx) + expf(s1 - mx) + expf(s2 - mx));
    int lab = labels[b];
    float sc = lab == 0 ? s0 : (lab == 1 ? s1 : s2);
    red[b] = lse - sc;
    __syncthreads();
    for (int st = 64; st > 0; st >>= 1) {
        if (b < st) red[b] += red[b + st];
        __syncthreads();
    }
    if (b == 0) out[0] = red[0] * (1.f / 128.f);
}

extern "C" void kernel_launch(void* const* d_in, const int* in_sizes, int n_in,
                              void* d_out, int out_size, void* d_ws, size_t ws_size,
                              hipStream_t stream) {
    const float* sents      = (const float*)d_in[0];
    const float* mask_table = (const float*)d_in[1];
    const float* gWihf      = (const float*)d_in[2];
    const float* gWhhf      = (const float*)d_in[3];
    const float* gbihf      = (const float*)d_in[4];
    const float* gbhhf      = (const float*)d_in[5];
    const float* gWihb      = (const float*)d_in[6];
    const float* gWhhb      = (const float*)d_in[7];
    const float* gbihb      = (const float*)d_in[8];
    const float* gbhhb      = (const float*)d_in[9];
    const float* hW         = (const float*)d_in[10];
    const float* hb         = (const float*)d_in[11];
    const float* tW         = (const float*)d_in[12];
    const float* tb         = (const float*)d_in[13];
    const float* trans      = (const float*)d_in[14];
    const float* lW         = (const float*)d_in[15];
    const float* lb         = (const float*)d_in[16];
    const int*   masks      = (const int*)d_in[17];
    const int*   lens       = (const int*)d_in[18];
    const int*   labels     = (const int*)d_in[19];

    char* wsb = (char*)d_ws;
    __hip_bfloat16* gi    = (__hip_bfloat16*)(wsb + OFF_GI);
    __hip_bfloat16* ctxb  = (__hip_bfloat16*)(wsb + OFF_CTXB);
    __hip_bfloat16* wihB  = (__hip_bfloat16*)(wsb + OFF_WIHB);
    __hip_bfloat16* whhB  = (__hip_bfloat16*)(wsb + OFF_WHHB);
    float* biasAll        = (float*)(wsb + OFF_BIAS);
    float* W2             = (float*)(wsb + OFF_W2);
    float* b2             = (float*)(wsb + OFF_B2);
    int* beg              = (int*)(wsb + OFF_BEG);
    int* tn               = (int*)(wsb + OFF_TN);
    float* scores         = (float*)(wsb + OFF_SCORES);
    float* fk             = (float*)(wsb + OFF_FK);
    float* alphas         = (float*)(wsb + OFF_AL);
    float* sp             = (float*)(wsb + OFF_SP);
    float* spsum          = (float*)(wsb + OFF_SPSUM);
    float* sv             = (float*)(wsb + OFF_SV);

    hipLaunchKernelGGL(k_prep_all, dim3(NB_WIH + NB_WHH + NB_W2 + 1), dim3(256), 0, stream,
                       gWihf, gWihb, gbihf, gbihb, gbhhf, gbhhb, gWhhf, gWhhb,
                       hW, hb, tW, tb, masks, wihB, biasAll, whhB, W2, b2, beg, tn);
    hipLaunchKernelGGL(k_mfma_gi, dim3(N2 / 64, MTOT / 64), dim3(256), 0, stream,
                       sents, mask_table, masks, (const short*)wihB, biasAll, gi);
    hipLaunchKernelGGL(k_gru_mfma, dim3(16), dim3(1024), 0, stream,
                       (const short*)gi, (const short*)whhB, gbhhf, gbhhb, lens, masks, beg, tn, ctxb);
    hipLaunchKernelGGL(k_fk, dim3(MTOT * 16 / 256), dim3(256), 0, stream,
                       ctxb, W2, b2, fk);
    hipLaunchKernelGGL(k_crf, dim3(32), dim3(64), 0, stream, fk, trans, lens, alphas, sp, spsum);
    hipLaunchKernelGGL(k_pool, dim3(BB), dim3(256), 0, stream, ctxb, sp, spsum, sv);
    hipLaunchKernelGGL(k_scores, dim3(BB), dim3(256), 0, stream, sv, lW, lb, scores);
    hipLaunchKernelGGL(k_final2, dim3(1), dim3(128), 0, stream, scores, labels, (float*)d_out);
}

// Round 8
// 1057.074 us; speedup vs baseline: 1.0968x; 1.0968x over previous
//
#include <hip/hip_runtime.h>
#include <hip/hip_bf16.h>

#define BB 128
#define LL 128
#define DD 300
#define MDIM 50
#define GINDIM 350
#define HDIM 256     // per-direction hidden
#define G3 768       // 3*HDIM
#define HH 512       // ctx dim
#define RR 128
#define TT 4
#define NKB 4        // branches
#define MTOT (BB*LL) // 16384
#define N2 1536      // both dirs stacked gates
#define KP 352       // padded GRU-input K

typedef __attribute__((ext_vector_type(8))) short short8;
typedef __attribute__((ext_vector_type(4))) float f32x4;

// ---------------- ws layout (bytes) ----------------
#define OFF_GI      0ull            // bf16 [2][16384][768] = 50,331,648
#define OFF_CTXB    50331648ull     // bf16 [16384][512] = 16,777,216
#define OFF_WIHB    78643200ull     // bf16 [1536][352]  = 1,081,344
#define OFF_WHHB    79724544ull     // bf16 [2][768][256]= 786,432
#define OFF_BIAS    80510976ull     // f32 [1536]
#define OFF_W2      80517120ull     // f32 [16][512] = 32,768
#define OFF_B2      80549888ull     // f32 [16]
#define OFF_BEG     80550144ull     // int [128]
#define OFF_TN      80550656ull     // int [128]
#define OFF_SCORES  80551168ull     // f32 [128][3]
#define OFF_FK      80553216ull     // f32 [4][16384][4] = 1,048,576
#define OFF_AL      81601792ull     // f32 [4][128][128][4] = 1,048,576
#define OFF_SP      82650368ull     // f32 [4][128][128] = 262,144
#define OFF_SPSUM   82912512ull     // f32 [4][128]
#define OFF_SV      82914560ull     // f32 [128][2048] = 1,048,576

__device__ __forceinline__ float sig_f(float x) { return 1.f / (1.f + __expf(-x)); }
__device__ __forceinline__ float tanh_f(float x) { float e = __expf(2.f * x); return 1.f - 2.f / (e + 1.f); }
__device__ __forceinline__ float b2f(unsigned short u) { return __uint_as_float(((unsigned)u) << 16); }

__device__ __forceinline__ void gload_lds16(const void* g, void* l) {
    __builtin_amdgcn_global_load_lds((const __attribute__((address_space(1))) unsigned int*)g,
                                     (__attribute__((address_space(3))) unsigned int*)l, 16, 0, 0);
}

// ---------------- merged prep: wihB+bias | whhB | W2+b2 | beg/tn ----------------
#define NB_WIH 2112   // 1536*352/256
#define NB_WHH 1536   // 2*768*256/256
#define NB_W2  32     // 16*512/256
__global__ __launch_bounds__(256) void k_prep_all(
        const float* __restrict__ gWihf, const float* __restrict__ gWihb,
        const float* __restrict__ gbihf, const float* __restrict__ gbihb,
        const float* __restrict__ gbhhf, const float* __restrict__ gbhhb,
        const float* __restrict__ gWhhf, const float* __restrict__ gWhhb,
        const float* __restrict__ hW, const float* __restrict__ hb,
        const float* __restrict__ tW, const float* __restrict__ tb,
        const int* __restrict__ masks,
        __hip_bfloat16* __restrict__ wihB, float* __restrict__ biasAll,
        __hip_bfloat16* __restrict__ whhB,
        float* __restrict__ W2, float* __restrict__ b2,
        int* __restrict__ beg, int* __restrict__ tn) {
    const int bid = blockIdx.x;
    const int t = threadIdx.x;
    if (bid < NB_WIH) {
        int idx = bid * 256 + t;
        int n = idx / KP, k = idx % KP;
        int dir = n >= G3; int g = n - dir * G3;
        const float* W = dir ? gWihb : gWihf;
        float v = (k < GINDIM) ? W[(size_t)g * GINDIM + k] : 0.f;
        wihB[idx] = __float2bfloat16(v);
        if (idx < N2) {
            int d2 = idx >= G3; int g2 = idx - d2 * G3;
            float b = d2 ? gbihb[g2] : gbihf[g2];
            if (g2 < 2 * HDIM) b += d2 ? gbhhb[g2] : gbhhf[g2];  // fold r,z hidden bias
            biasAll[idx] = b;
        }
    } else if (bid < NB_WIH + NB_WHH) {
        int idx = (bid - NB_WIH) * 256 + t;
        int dir = idx / (G3 * HDIM);
        const float* W = dir ? gWhhb : gWhhf;
        whhB[idx] = __float2bfloat16(W[idx - dir * G3 * HDIM]);
    } else if (bid < NB_WIH + NB_WHH + NB_W2) {
        int idx = (bid - NB_WIH - NB_WHH) * 256 + t;
        int kt = idx >> 9, h = idx & 511;
        int k = kt >> 2, tt = kt & 3;
        const float* tw = tW + (size_t)(k * TT + tt) * RR;
        const float* hw = hW + (size_t)k * RR * HH + h;
        float acc = 0.f;
        #pragma unroll 4
        for (int r = 0; r < RR; ++r) acc += tw[r] * hw[(size_t)r * HH];
        W2[idx] = acc;
        if (idx < 16) {
            int k2 = idx >> 2, t2 = idx & 3;
            const float* tw2 = tW + (size_t)(k2 * TT + t2) * RR;
            const float* hbk = hb + k2 * RR;
            float a = tb[k2 * TT + t2];
            for (int r = 0; r < RR; ++r) a += tw2[r] * hbk[r];
            b2[idx] = a;
        }
    } else {
        if (t < 128) {
            int b = t;
            int best = masks[b * LL]; int idx = 0; int s = 0;
            for (int j = 0; j < LL; ++j) {
                int v = masks[b * LL + j]; s += v;
                if (v > best) { best = v; idx = j; }
            }
            beg[b] = idx; tn[b] = s;
        }
    }
}

// ---------------- MFMA GEMM 1: gi = x @ Wih^T + bias (x built inline from sents) ----------------
__global__ __launch_bounds__(256) void k_mfma_gi(const float* __restrict__ sents,
        const float* __restrict__ mask_table, const int* __restrict__ masks,
        const short* __restrict__ wihB, const float* __restrict__ biasAll,
        __hip_bfloat16* __restrict__ gi) {
    __shared__ short As[64][40];
    __shared__ short Bs[64][40];
    const int tid = threadIdx.x;
    const int m0 = blockIdx.y * 64, n0 = blockIdx.x * 64;
    const int w = tid >> 6, lane = tid & 63;
    const int srow = tid >> 2, skc = (tid & 3) * 8;
    const int frow = lane & 15, fkc = (lane >> 4) * 8;
    const int rb = (w >> 1) * 32, cb = (w & 1) * 32;
    const int m = m0 + srow;
    const float* sr = sents + (size_t)m * DD;
    const float* mr = mask_table + masks[m] * MDIM;
    f32x4 zero = {0.f, 0.f, 0.f, 0.f};
    f32x4 acc[2][2] = {zero, zero, zero, zero};
    for (int k0 = 0; k0 < KP; k0 += 32) {
        short8 av;
        #pragma unroll
        for (int j = 0; j < 8; ++j) {
            int k = k0 + skc + j;
            float v = (k < DD) ? sr[k] : ((k < GINDIM) ? mr[k - DD] : 0.f);
            __hip_bfloat16 bb = __float2bfloat16(v);
            av[j] = *reinterpret_cast<short*>(&bb);
        }
        *(short8*)&As[srow][skc] = av;
        *(short8*)&Bs[srow][skc] = *(const short8*)&wihB[(size_t)(n0 + srow) * KP + k0 + skc];
        __syncthreads();
        short8 a[2], b[2];
        #pragma unroll
        for (int i = 0; i < 2; ++i) a[i] = *(const short8*)&As[rb + i * 16 + frow][fkc];
        #pragma unroll
        for (int j = 0; j < 2; ++j) b[j] = *(const short8*)&Bs[cb + j * 16 + frow][fkc];
        #pragma unroll
        for (int i = 0; i < 2; ++i)
            #pragma unroll
            for (int j = 0; j < 2; ++j)
                acc[i][j] = __builtin_amdgcn_mfma_f32_16x16x32_bf16(a[i], b[j], acc[i][j], 0, 0, 0);
        __syncthreads();
    }
    #pragma unroll
    for (int i = 0; i < 2; ++i) {
        #pragma unroll
        for (int j = 0; j < 2; ++j) {
            int col = n0 + cb + j * 16 + frow;
            int dir = col >= G3; int g = col - dir * G3;
            float bias = biasAll[col];
            #pragma unroll
            for (int r = 0; r < 4; ++r) {
                int mm = m0 + rb + i * 16 + (lane >> 4) * 4 + r;
                gi[((size_t)dir * MTOT + mm) * G3 + g] = __float2bfloat16(acc[i][j][r] + bias);
            }
        }
    }
}

// ---------------- pos weight ----------------
__device__ __forceinline__ float poswt(int j, int beg, int tn, int len, float lf, int mv) {
    float w = (j < beg) ? (1.f - (float)(beg - j) / lf) : 0.f;
    if (mv == 1) w = 1.f;
    if (j > beg + tn) w = 1.f - (float)(j - beg) / lf;
    if (j > len) w = 0.f;
    return w;
}

// ---------------- GRU recurrence via MFMA: 16 blocks x 512 threads (8 waves) ----------------
// Wave w owns 96 gate cols (6 col-tiles): 48 B-frags = 192 VGPR, pinned.
// gi staged per-step into LDS via global_load_lds (zero VGPR cost).
#define LB(ct,kk) short8 bu_##ct##_##kk = *(const short8*)(wB + (ct * 16) * HDIM + (kk) * 32);
#define LBCT(ct) LB(ct,0) LB(ct,1) LB(ct,2) LB(ct,3) LB(ct,4) LB(ct,5) LB(ct,6) LB(ct,7)
#define KEEP(ct,kk) asm volatile("" : "+v"(bu_##ct##_##kk));
#define KEEPCT(ct) KEEP(ct,0) KEEP(ct,1) KEEP(ct,2) KEEP(ct,3) KEEP(ct,4) KEEP(ct,5) KEEP(ct,6) KEEP(ct,7)
#define MM(kk) { const short8 a = *(const short8*)(aB + (kk) * 32); \
    acc0 = __builtin_amdgcn_mfma_f32_16x16x32_bf16(a, bu_0_##kk, acc0, 0, 0, 0); \
    acc1 = __builtin_amdgcn_mfma_f32_16x16x32_bf16(a, bu_1_##kk, acc1, 0, 0, 0); \
    acc2 = __builtin_amdgcn_mfma_f32_16x16x32_bf16(a, bu_2_##kk, acc2, 0, 0, 0); \
    acc3 = __builtin_amdgcn_mfma_f32_16x16x32_bf16(a, bu_3_##kk, acc3, 0, 0, 0); \
    acc4 = __builtin_amdgcn_mfma_f32_16x16x32_bf16(a, bu_4_##kk, acc4, 0, 0, 0); \
    acc5 = __builtin_amdgcn_mfma_f32_16x16x32_bf16(a, bu_5_##kk, acc5, 0, 0, 0); }
#define GW(ct,accv) { const int col = colg + ct * 16 + frow; \
    gates[r0 + 0][col] = accv[0]; gates[r0 + 1][col] = accv[1]; \
    gates[r0 + 2][col] = accv[2]; gates[r0 + 3][col] = accv[3]; }
#define NQ(q, hvq) { \
    const int bl = bbase + q; \
    const int len = s_len[bl]; \
    const bool valid = l < len; \
    int pos = dir ? (len - 1 - l) : l; \
    if (!valid) pos = 0; \
    const short* gb = &giLds[bl * G3]; \
    float rr = sig_f(b2f((unsigned short)gb[i_idx]) + gates[bl][i_idx]); \
    float zz = sig_f(b2f((unsigned short)gb[HDIM + i_idx]) + gates[bl][HDIM + i_idx]); \
    float nn = tanh_f(b2f((unsigned short)gb[2 * HDIM + i_idx]) + rr * (gates[bl][2 * HDIM + i_idx] + bhn)); \
    float h = (1.f - zz) * nn + zz * hvq; \
    if (valid) { \
        hvq = h; \
        __hip_bfloat16 hb16 = __float2bfloat16(h); \
        hA[bl][i_idx] = *(short*)&hb16; \
        float hw = h * s_w[bl][pos]; \
        ctxb[((size_t)(b0 + bl) * LL + pos) * HH + dirH + i_idx] = __float2bfloat16(hw); \
    } }

__global__ __launch_bounds__(512, 2)
void k_gru_mfma(
        const short* __restrict__ gi, const short* __restrict__ whhB,
        const float* __restrict__ gbhhf, const float* __restrict__ gbhhb,
        const int* __restrict__ lens, const int* __restrict__ masks,
        const int* __restrict__ beg_, const int* __restrict__ tn_,
        __hip_bfloat16* __restrict__ ctxb) {
    __shared__ float gates[16][772];     // 49,408 B
    __shared__ short hA[16][264];        //  8,448 B
    __shared__ float s_w[16][128];       //  8,192 B
    __shared__ short giLds[16 * G3];     // 24,576 B (current-step gi rows)
    __shared__ int s_len[16];
    __shared__ int s_maxlen;

    const int tid = threadIdx.x;
    const int w = tid >> 6, lane = tid & 63;
    const int dir = blockIdx.x >> 3, grp = blockIdx.x & 7;
    const int b0 = grp * 16;
    const int frow = lane & 15, fkc = (lane >> 4) * 8;
    const int colg = w * 96;
    const int r0 = (lane >> 4) * 4;
    const int dirH = dir * HDIM;

    if (tid < 16) s_len[tid] = lens[b0 + tid];
    for (int e = tid; e < 16 * 264; e += 512) ((short*)hA)[e] = 0;
    __syncthreads();
    if (tid == 0) {
        int m = 0;
        #pragma unroll
        for (int q = 0; q < 16; ++q) m = max(m, s_len[q]);
        s_maxlen = m;
    }
    for (int e = tid; e < 16 * 128; e += 512) {
        int bl = e >> 7, j = e & 127;
        int b = b0 + bl;
        int len = s_len[bl];
        s_w[bl][j] = poswt(j, beg_[b], tn_[b], len, (float)len, masks[b * LL + j]);
    }

    // ---- B fragments: 48 named short8 (192 VGPR), loaded once, pinned ----
    const short* wB = whhB + ((size_t)dir * G3 + colg + frow) * HDIM + fkc;
    LBCT(0) LBCT(1) LBCT(2) LBCT(3) LBCT(4) LBCT(5)
    KEEPCT(0) KEEPCT(1) KEEPCT(2) KEEPCT(3) KEEPCT(4) KEEPCT(5)

    const int i_idx = tid & 255;
    const int bbase = (tid >> 8) * 8;    // 8 batches per thread
    const float bhn = (dir ? gbhhb : gbhhf)[2 * HDIM + i_idx];
    const short* giD = gi + (size_t)dir * MTOT * G3;
    const short* aB = &hA[frow][fkc];
    float hv0 = 0.f, hv1 = 0.f, hv2 = 0.f, hv3 = 0.f, hv4 = 0.f, hv5 = 0.f, hv6 = 0.f, hv7 = 0.f;
    __syncthreads();
    const int maxlen = s_maxlen;

    const f32x4 zero = {0.f, 0.f, 0.f, 0.f};
    for (int l = 0; l < maxlen; ++l) {
        // ---- stage this step's gi rows into LDS (async; drained by barrier) ----
        #pragma unroll
        for (int j = 0; j < 3; ++j) {
            int flat = j * 512 + tid;            // 16B-chunk id, 0..1535
            int bl = flat / 96;
            int off16 = flat - bl * 96;
            int len = s_len[bl];
            int pos = dir ? (len - 1 - l) : l;
            if (l >= len) pos = 0;
            const char* src = (const char*)giD + ((size_t)((b0 + bl) * LL + pos) * G3 + off16 * 8) * 2;
            short* dst = &giLds[(j * 512 + (tid & ~63)) * 8];
            gload_lds16(src, dst);
        }
        // ---- MFMA: gates_pre = h @ Whh^T (fully static unrolled) ----
        f32x4 acc0 = zero, acc1 = zero, acc2 = zero, acc3 = zero, acc4 = zero, acc5 = zero;
        MM(0) MM(1) MM(2) MM(3) MM(4) MM(5) MM(6) MM(7)
        GW(0, acc0) GW(1, acc1) GW(2, acc2) GW(3, acc3) GW(4, acc4) GW(5, acc5)
        __syncthreads();   // gates + staged gi visible
        // ---- nonlinearity ----
        NQ(0, hv0) NQ(1, hv1) NQ(2, hv2) NQ(3, hv3)
        NQ(4, hv4) NQ(5, hv5) NQ(6, hv6) NQ(7, hv7)
        __syncthreads();   // hA update visible before next MFMA
        KEEPCT(0) KEEPCT(1) KEEPCT(2) KEEPCT(3) KEEPCT(4) KEEPCT(5)
    }
}

// ---------------- fused fk = ctxb @ W2^T + b2 ----------------
__global__ __launch_bounds__(256) void k_fk(const __hip_bfloat16* __restrict__ ctxb,
        const float* __restrict__ W2, const float* __restrict__ b2,
        float* __restrict__ fk) {
    int gid = blockIdx.x * 256 + threadIdx.x;  // MTOT*16
    int m = gid >> 4, kt = gid & 15;
    const short8* crow = (const short8*)((const short*)ctxb + (size_t)m * HH);
    const float* w2 = W2 + kt * HH;
    float acc = b2[kt];
    #pragma unroll 4
    for (int c = 0; c < HH / 8; ++c) {
        short8 v = crow[c];
        #pragma unroll
        for (int j = 0; j < 8; ++j)
            acc += b2f((unsigned short)v[j]) * w2[c * 8 + j];
    }
    fk[((size_t)(kt >> 2) * MTOT + m) * TT + (kt & 3)] = acc;
}

// ---------------- CRF forward/backward marginals (4 lanes per (k,b)) ----------------
__global__ __launch_bounds__(64) void k_crf(const float* __restrict__ fk,
        const float* __restrict__ trans, const int* __restrict__ lens,
        float* __restrict__ alphas, float* __restrict__ sp, float* __restrict__ spsum) {
    const int tid = blockIdx.x * 64 + threadIdx.x;   // 2048 total
    const int pid = tid >> 2;                        // 512 pairs
    const int t = tid & 3;
    const int k = pid >> 7, b = pid & 127;
    const int len = lens[b];
    const float* f = fk + ((size_t)k * MTOT + (size_t)b * LL) * TT;
    const float* tr = trans + k * 16;
    const float trC0 = tr[0 * 4 + t], trC1 = tr[1 * 4 + t], trC2 = tr[2 * 4 + t], trC3 = tr[3 * 4 + t];
    const float trR0 = tr[t * 4 + 0], trR1 = tr[t * 4 + 1], trR2 = tr[t * 4 + 2], trR3 = tr[t * 4 + 3];
    float* al = alphas + ((size_t)k * BB + b) * LL * TT;
    const int base = threadIdx.x & ~3;
    float alpha = f[t];
    al[t] = alpha;
    for (int l = 1; l < LL; ++l) {
        float a0 = __shfl(alpha, base + 0);
        float a1 = __shfl(alpha, base + 1);
        float a2 = __shfl(alpha, base + 2);
        float a3 = __shfl(alpha, base + 3);
        float v0 = a0 + trC0, v1 = a1 + trC1, v2 = a2 + trC2, v3 = a3 + trC3;
        float mx = fmaxf(fmaxf(v0, v1), fmaxf(v2, v3));
        float sum = __expf(v0 - mx) + __expf(v1 - mx) + __expf(v2 - mx) + __expf(v3 - mx);
        float nw = mx + __logf(sum) + f[l * TT + t];
        if (l < len) alpha = nw;
        al[l * TT + t] = alpha;
    }
    float beta = 0.f;
    float ssum = 0.f;
    for (int l = LL - 1; l >= 0; --l) {
        if (l < LL - 1) {
            float fb = f[(l + 1) * TT + t] + beta;
            float c0 = __shfl(fb, base + 0);
            float c1 = __shfl(fb, base + 1);
            float c2 = __shfl(fb, base + 2);
            float c3 = __shfl(fb, base + 3);
            float w0 = trR0 + c0, w1 = trR1 + c1, w2 = trR2 + c2, w3 = trR3 + c3;
            float mx = fmaxf(fmaxf(w0, w1), fmaxf(w2, w3));
            float nb = mx + __logf(__expf(w0 - mx) + __expf(w1 - mx) + __expf(w2 - mx) + __expf(w3 - mx));
            if (l + 1 < len) beta = nb;
        }
        float v = al[l * TT + t] + beta;
        float mx = fmaxf(v, __shfl_xor(v, 1));
        mx = fmaxf(mx, __shfl_xor(mx, 2));
        float p = __expf(v - mx);
        float s = p;
        s += __shfl_xor(s, 1);
        s += __shfl_xor(s, 2);
        float m1 = __shfl(p, base + 1) / s;
        float spv = (l < len) ? m1 : 0.f;
        if (t == 0) sp[((size_t)k * BB + b) * LL + l] = spv;
        ssum += spv;
    }
    if (t == 0) spsum[k * BB + b] = ssum;
}

// ---------------- pooling: sv[b, k*512+h] (bf16 ctx, vectorized) ----------------
__global__ __launch_bounds__(256) void k_pool(const __hip_bfloat16* __restrict__ ctxb,
        const float* __restrict__ sp, const float* __restrict__ spsum,
        float* __restrict__ sv) {
    __shared__ float s_sp[NKB][LL];
    __shared__ float s_inv[NKB];
    const int b = blockIdx.x;
    const int tid = threadIdx.x;
    for (int i = tid; i < NKB * LL; i += 256) {
        int k = i >> 7, l = i & 127;
        s_sp[k][l] = sp[((size_t)k * BB + b) * LL + l];
    }
    if (tid < NKB) s_inv[tid] = 1.f / spsum[tid * BB + b];
    __syncthreads();
    const int n0 = tid * 8;
    const int k = n0 >> 9, h0 = n0 & 511;
    float acc[8] = {};
    const short* cb = (const short*)ctxb;
    for (int l = 0; l < LL; ++l) {
        float spl = s_sp[k][l];
        short8 v = *(const short8*)&cb[((size_t)b * LL + l) * HH + h0];
        #pragma unroll
        for (int j = 0; j < 8; ++j)
            acc[j] += spl * b2f((unsigned short)v[j]);
    }
    float inv = s_inv[k];
    #pragma unroll
    for (int j = 0; j < 8; ++j)
        sv[(size_t)b * 2048 + n0 + j] = acc[j] * inv;
}

// ---------------- scores[b][3] = relu(sv[b]) @ lW^T + lb ----------------
__global__ __launch_bounds__(256) void k_scores(const float* __restrict__ sv,
        const float* __restrict__ lW, const float* __restrict__ lb,
        float* __restrict__ scores) {
    __shared__ float red[3][4];
    const int b = blockIdx.x;
    const int tid = threadIdx.x;
    const float* svb = sv + (size_t)b * 2048;
    float a0 = 0.f, a1 = 0.f, a2 = 0.f;
    for (int i = tid; i < 2048; i += 256) {
        float v = fmaxf(svb[i], 0.f);
        a0 += v * lW[i];
        a1 += v * lW[2048 + i];
        a2 += v * lW[4096 + i];
    }
    #pragma unroll
    for (int off = 32; off > 0; off >>= 1) {
        a0 += __shfl_down(a0, off);
        a1 += __shfl_down(a1, off);
        a2 += __shfl_down(a2, off);
    }
    const int wid = tid >> 6, lane = tid & 63;
    if (lane == 0) { red[0][wid] = a0; red[1][wid] = a1; red[2][wid] = a2; }
    __syncthreads();
    if (tid < 3) {
        scores[b * 3 + tid] = red[tid][0] + red[tid][1] + red[tid][2] + red[tid][3] + lb[tid];
    }
}

// ---------------- final: log-softmax + mean NLL (float32 out) ----------------
__global__ __launch_bounds__(128) void k_final2(const float* __restrict__ scores,
        const int* __restrict__ labels, float* __restrict__ out) {
    __shared__ float red[128];
    const int b = threadIdx.x;
    float s0 = scores[b * 3 + 0], s1 = scores[b * 3 + 1], s2 = scores[b * 3 + 2];
    float mx = fmaxf(s0, fmaxf(s1, s2));
    float lse = mx + logf(expf(s0 - mx) + expf(s1 - mx) + expf(s2 - mx));
    int lab = labels[b];
    float sc = lab == 0 ? s0 : (lab == 1 ? s1 : s2);
    red[b] = lse - sc;
    __syncthreads();
    for (int st = 64; st > 0; st >>= 1) {
        if (b < st) red[b] += red[b + st];
        __syncthreads();
    }
    if (b == 0) out[0] = red[0] * (1.f / 128.f);
}

extern "C" void kernel_launch(void* const* d_in, const int* in_sizes, int n_in,
                              void* d_out, int out_size, void* d_ws, size_t ws_size,
                              hipStream_t stream) {
    const float* sents      = (const float*)d_in[0];
    const float* mask_table = (const float*)d_in[1];
    const float* gWihf      = (const float*)d_in[2];
    const float* gWhhf      = (const float*)d_in[3];
    const float* gbihf      = (const float*)d_in[4];
    const float* gbhhf      = (const float*)d_in[5];
    const float* gWihb      = (const float*)d_in[6];
    const float* gWhhb      = (const float*)d_in[7];
    const float* gbihb      = (const float*)d_in[8];
    const float* gbhhb      = (const float*)d_in[9];
    const float* hW         = (const float*)d_in[10];
    const float* hb         = (const float*)d_in[11];
    const float* tW         = (const float*)d_in[12];
    const float* tb         = (const float*)d_in[13];
    const float* trans      = (const float*)d_in[14];
    const float* lW         = (const float*)d_in[15];
    const float* lb         = (const float*)d_in[16];
    const int*   masks      = (const int*)d_in[17];
    const int*   lens       = (const int*)d_in[18];
    const int*   labels     = (const int*)d_in[19];

    char* wsb = (char*)d_ws;
    __hip_bfloat16* gi    = (__hip_bfloat16*)(wsb + OFF_GI);
    __hip_bfloat16* ctxb  = (__hip_bfloat16*)(wsb + OFF_CTXB);
    __hip_bfloat16* wihB  = (__hip_bfloat16*)(wsb + OFF_WIHB);
    __hip_bfloat16* whhB  = (__hip_bfloat16*)(wsb + OFF_WHHB);
    float* biasAll        = (float*)(wsb + OFF_BIAS);
    float* W2             = (float*)(wsb + OFF_W2);
    float* b2             = (float*)(wsb + OFF_B2);
    int* beg              = (int*)(wsb + OFF_BEG);
    int* tn               = (int*)(wsb + OFF_TN);
    float* scores         = (float*)(wsb + OFF_SCORES);
    float* fk             = (float*)(wsb + OFF_FK);
    float* alphas         = (float*)(wsb + OFF_AL);
    float* sp             = (float*)(wsb + OFF_SP);
    float* spsum          = (float*)(wsb + OFF_SPSUM);
    float* sv             = (float*)(wsb + OFF_SV);

    hipLaunchKernelGGL(k_prep_all, dim3(NB_WIH + NB_WHH + NB_W2 + 1), dim3(256), 0, stream,
                       gWihf, gWihb, gbihf, gbihb, gbhhf, gbhhb, gWhhf, gWhhb,
                       hW, hb, tW, tb, masks, wihB, biasAll, whhB, W2, b2, beg, tn);
    hipLaunchKernelGGL(k_mfma_gi, dim3(N2 / 64, MTOT / 64), dim3(256), 0, stream,
                       sents, mask_table, masks, (const short*)wihB, biasAll, gi);
    hipLaunchKernelGGL(k_gru_mfma, dim3(16), dim3(512), 0, stream,
                       (const short*)gi, (const short*)whhB, gbhhf, gbhhb, lens, masks, beg, tn, ctxb);
    hipLaunchKernelGGL(k_fk, dim3(MTOT * 16 / 256), dim3(256), 0, stream,
                       ctxb, W2, b2, fk);
    hipLaunchKernelGGL(k_crf, dim3(32), dim3(64), 0, stream, fk, trans, lens, alphas, sp, spsum);
    hipLaunchKernelGGL(k_pool, dim3(BB), dim3(256), 0, stream, ctxb, sp, spsum, sv);
    hipLaunchKernelGGL(k_scores, dim3(BB), dim3(256), 0, stream, sv, lW, lb, scores);
    hipLaunchKernelGGL(k_final2, dim3(1), dim3(128), 0, stream, scores, labels, (float*)d_out);
}

// Round 9
// 807.711 us; speedup vs baseline: 1.4355x; 1.3087x over previous
//
#include <hip/hip_runtime.h>
#include <hip/hip_bf16.h>

#define BB 128
#define LL 128
#define DD 300
#define MDIM 50
#define GINDIM 350
#define HDIM 256     // per-direction hidden
#define G3 768       // 3*HDIM
#define HH 512       // ctx dim
#define RR 128
#define TT 4
#define NKB 4        // branches
#define MTOT (BB*LL) // 16384
#define N2 1536      // both dirs stacked gates
#define KP 352       // padded GRU-input K

typedef __attribute__((ext_vector_type(8))) short short8;
typedef __attribute__((ext_vector_type(4))) float f32x4;

// ---------------- ws layout (bytes) ----------------
#define OFF_GI      0ull            // bf16 [2][16384][768] = 50,331,648
#define OFF_CTXB    50331648ull     // bf16 [16384][512] = 16,777,216
#define OFF_WIHB    78643200ull     // bf16 [1536][352]  = 1,081,344
#define OFF_WHHB    79724544ull     // fp8 [2][768][256] = 393,216
#define OFF_BIAS    80510976ull     // f32 [1536]
#define OFF_W2      80517120ull     // f32 [16][512] = 32,768
#define OFF_B2      80549888ull     // f32 [16]
#define OFF_BEG     80550144ull     // int [128]
#define OFF_TN      80550656ull     // int [128]
#define OFF_SCORES  80551168ull     // f32 [128][3]
#define OFF_FK      80553216ull     // f32 [4][16384][4] = 1,048,576
#define OFF_AL      81601792ull     // f32 [4][128][128][4] = 1,048,576
#define OFF_SP      82650368ull     // f32 [4][128][128] = 262,144
#define OFF_SPSUM   82912512ull     // f32 [4][128]
#define OFF_SV      82914560ull     // f32 [128][2048] = 1,048,576

__device__ __forceinline__ float sig_f(float x) { return 1.f / (1.f + __expf(-x)); }
__device__ __forceinline__ float tanh_f(float x) { float e = __expf(2.f * x); return 1.f - 2.f / (e + 1.f); }
__device__ __forceinline__ float b2f(unsigned short u) { return __uint_as_float(((unsigned)u) << 16); }
__device__ __forceinline__ unsigned char f2fp8(float v) {
    return (unsigned char)(__builtin_amdgcn_cvt_pk_fp8_f32(v, 0.f, 0, false) & 0xff);
}

__device__ __forceinline__ void gload_lds16(const void* g, void* l) {
    __builtin_amdgcn_global_load_lds((const __attribute__((address_space(1))) unsigned int*)g,
                                     (__attribute__((address_space(3))) unsigned int*)l, 16, 0, 0);
}

// ---------------- merged prep: wihB+bias | whhB(fp8) | W2+b2 | beg/tn ----------------
#define NB_WIH 2112   // 1536*352/256
#define NB_WHH 1536   // 2*768*256 bytes /256
#define NB_W2  32     // 16*512/256
__global__ __launch_bounds__(256) void k_prep_all(
        const float* __restrict__ gWihf, const float* __restrict__ gWihb,
        const float* __restrict__ gbihf, const float* __restrict__ gbihb,
        const float* __restrict__ gbhhf, const float* __restrict__ gbhhb,
        const float* __restrict__ gWhhf, const float* __restrict__ gWhhb,
        const float* __restrict__ hW, const float* __restrict__ hb,
        const float* __restrict__ tW, const float* __restrict__ tb,
        const int* __restrict__ masks,
        __hip_bfloat16* __restrict__ wihB, float* __restrict__ biasAll,
        unsigned char* __restrict__ whhB,
        float* __restrict__ W2, float* __restrict__ b2,
        int* __restrict__ beg, int* __restrict__ tn) {
    const int bid = blockIdx.x;
    const int t = threadIdx.x;
    if (bid < NB_WIH) {
        int idx = bid * 256 + t;
        int n = idx / KP, k = idx % KP;
        int dir = n >= G3; int g = n - dir * G3;
        const float* W = dir ? gWihb : gWihf;
        float v = (k < GINDIM) ? W[(size_t)g * GINDIM + k] : 0.f;
        wihB[idx] = __float2bfloat16(v);
        if (idx < N2) {
            int d2 = idx >= G3; int g2 = idx - d2 * G3;
            float b = d2 ? gbihb[g2] : gbihf[g2];
            if (g2 < 2 * HDIM) b += d2 ? gbhhb[g2] : gbhhf[g2];  // fold r,z hidden bias
            biasAll[idx] = b;
        }
    } else if (bid < NB_WIH + NB_WHH) {
        int idx = (bid - NB_WIH) * 256 + t;
        int dir = idx / (G3 * HDIM);
        const float* W = dir ? gWhhb : gWhhf;
        whhB[idx] = f2fp8(W[idx - dir * G3 * HDIM]);
    } else if (bid < NB_WIH + NB_WHH + NB_W2) {
        int idx = (bid - NB_WIH - NB_WHH) * 256 + t;
        int kt = idx >> 9, h = idx & 511;
        int k = kt >> 2, tt = kt & 3;
        const float* tw = tW + (size_t)(k * TT + tt) * RR;
        const float* hw = hW + (size_t)k * RR * HH + h;
        float acc = 0.f;
        #pragma unroll 4
        for (int r = 0; r < RR; ++r) acc += tw[r] * hw[(size_t)r * HH];
        W2[idx] = acc;
        if (idx < 16) {
            int k2 = idx >> 2, t2 = idx & 3;
            const float* tw2 = tW + (size_t)(k2 * TT + t2) * RR;
            const float* hbk = hb + k2 * RR;
            float a = tb[k2 * TT + t2];
            for (int r = 0; r < RR; ++r) a += tw2[r] * hbk[r];
            b2[idx] = a;
        }
    } else {
        if (t < 128) {
            int b = t;
            int best = masks[b * LL]; int idx = 0; int s = 0;
            for (int j = 0; j < LL; ++j) {
                int v = masks[b * LL + j]; s += v;
                if (v > best) { best = v; idx = j; }
            }
            beg[b] = idx; tn[b] = s;
        }
    }
}

// ---------------- MFMA GEMM 1: gi = x @ Wih^T + bias (x built inline from sents) ----------------
__global__ __launch_bounds__(256) void k_mfma_gi(const float* __restrict__ sents,
        const float* __restrict__ mask_table, const int* __restrict__ masks,
        const short* __restrict__ wihB, const float* __restrict__ biasAll,
        __hip_bfloat16* __restrict__ gi) {
    __shared__ short As[64][40];
    __shared__ short Bs[64][40];
    const int tid = threadIdx.x;
    const int m0 = blockIdx.y * 64, n0 = blockIdx.x * 64;
    const int w = tid >> 6, lane = tid & 63;
    const int srow = tid >> 2, skc = (tid & 3) * 8;
    const int frow = lane & 15, fkc = (lane >> 4) * 8;
    const int rb = (w >> 1) * 32, cb = (w & 1) * 32;
    const int m = m0 + srow;
    const float* sr = sents + (size_t)m * DD;
    const float* mr = mask_table + masks[m] * MDIM;
    f32x4 zero = {0.f, 0.f, 0.f, 0.f};
    f32x4 acc[2][2] = {zero, zero, zero, zero};
    for (int k0 = 0; k0 < KP; k0 += 32) {
        short8 av;
        #pragma unroll
        for (int j = 0; j < 8; ++j) {
            int k = k0 + skc + j;
            float v = (k < DD) ? sr[k] : ((k < GINDIM) ? mr[k - DD] : 0.f);
            __hip_bfloat16 bb = __float2bfloat16(v);
            av[j] = *reinterpret_cast<short*>(&bb);
        }
        *(short8*)&As[srow][skc] = av;
        *(short8*)&Bs[srow][skc] = *(const short8*)&wihB[(size_t)(n0 + srow) * KP + k0 + skc];
        __syncthreads();
        short8 a[2], b[2];
        #pragma unroll
        for (int i = 0; i < 2; ++i) a[i] = *(const short8*)&As[rb + i * 16 + frow][fkc];
        #pragma unroll
        for (int j = 0; j < 2; ++j) b[j] = *(const short8*)&Bs[cb + j * 16 + frow][fkc];
        #pragma unroll
        for (int i = 0; i < 2; ++i)
            #pragma unroll
            for (int j = 0; j < 2; ++j)
                acc[i][j] = __builtin_amdgcn_mfma_f32_16x16x32_bf16(a[i], b[j], acc[i][j], 0, 0, 0);
        __syncthreads();
    }
    #pragma unroll
    for (int i = 0; i < 2; ++i) {
        #pragma unroll
        for (int j = 0; j < 2; ++j) {
            int col = n0 + cb + j * 16 + frow;
            int dir = col >= G3; int g = col - dir * G3;
            float bias = biasAll[col];
            #pragma unroll
            for (int r = 0; r < 4; ++r) {
                int mm = m0 + rb + i * 16 + (lane >> 4) * 4 + r;
                gi[((size_t)dir * MTOT + mm) * G3 + g] = __float2bfloat16(acc[i][j][r] + bias);
            }
        }
    }
}

// ---------------- pos weight ----------------
__device__ __forceinline__ float poswt(int j, int beg, int tn, int len, float lf, int mv) {
    float w = (j < beg) ? (1.f - (float)(beg - j) / lf) : 0.f;
    if (mv == 1) w = 1.f;
    if (j > beg + tn) w = 1.f - (float)(j - beg) / lf;
    if (j > len) w = 0.f;
    return w;
}

// ---------------- GRU recurrence via fp8 MFMA: 16 blocks x 512 threads (8 waves) ----------------
// Wave w owns 96 gate cols: 48 fp8 B-frags = 96 VGPR (fits the 128 arch-VGPR half).
#define LB(ct,kk) long bu_##ct##_##kk = *(const long*)(wB + (ct * 16) * HDIM + (kk) * 32);
#define LBCT(ct) LB(ct,0) LB(ct,1) LB(ct,2) LB(ct,3) LB(ct,4) LB(ct,5) LB(ct,6) LB(ct,7)
#define KEEP(ct,kk) asm volatile("" : "+v"(bu_##ct##_##kk));
#define KEEPCT(ct) KEEP(ct,0) KEEP(ct,1) KEEP(ct,2) KEEP(ct,3) KEEP(ct,4) KEEP(ct,5) KEEP(ct,6) KEEP(ct,7)
#define MM(kk) { const long a = *(const long*)(aB + (kk) * 32); \
    acc0 = __builtin_amdgcn_mfma_f32_16x16x32_fp8_fp8(a, bu_0_##kk, acc0, 0, 0, 0); \
    acc1 = __builtin_amdgcn_mfma_f32_16x16x32_fp8_fp8(a, bu_1_##kk, acc1, 0, 0, 0); \
    acc2 = __builtin_amdgcn_mfma_f32_16x16x32_fp8_fp8(a, bu_2_##kk, acc2, 0, 0, 0); \
    acc3 = __builtin_amdgcn_mfma_f32_16x16x32_fp8_fp8(a, bu_3_##kk, acc3, 0, 0, 0); \
    acc4 = __builtin_amdgcn_mfma_f32_16x16x32_fp8_fp8(a, bu_4_##kk, acc4, 0, 0, 0); \
    acc5 = __builtin_amdgcn_mfma_f32_16x16x32_fp8_fp8(a, bu_5_##kk, acc5, 0, 0, 0); }
#define GW(ct,accv) { const int col = colg + ct * 16 + frow; \
    gates[r0 + 0][col] = accv[0]; gates[r0 + 1][col] = accv[1]; \
    gates[r0 + 2][col] = accv[2]; gates[r0 + 3][col] = accv[3]; }
#define NQ(q, hvq) { \
    const int bl = bbase + q; \
    const int len = s_len[bl]; \
    const bool valid = l < len; \
    int pos = dir ? (len - 1 - l) : l; \
    if (!valid) pos = 0; \
    const short* gb = &giLds[bl * G3]; \
    float rr = sig_f(b2f((unsigned short)gb[i_idx]) + gates[bl][i_idx]); \
    float zz = sig_f(b2f((unsigned short)gb[HDIM + i_idx]) + gates[bl][HDIM + i_idx]); \
    float nn = tanh_f(b2f((unsigned short)gb[2 * HDIM + i_idx]) + rr * (gates[bl][2 * HDIM + i_idx] + bhn)); \
    float h = (1.f - zz) * nn + zz * hvq; \
    if (valid) { \
        hvq = h; \
        hA[bl][i_idx] = f2fp8(h); \
        float hw = h * s_w[bl][pos]; \
        ctxb[((size_t)(b0 + bl) * LL + pos) * HH + dirH + i_idx] = __float2bfloat16(hw); \
    } }

__global__ __launch_bounds__(512, 2)
void k_gru_mfma(
        const short* __restrict__ gi, const unsigned char* __restrict__ whhB,
        const float* __restrict__ gbhhf, const float* __restrict__ gbhhb,
        const int* __restrict__ lens, const int* __restrict__ masks,
        const int* __restrict__ beg_, const int* __restrict__ tn_,
        __hip_bfloat16* __restrict__ ctxb) {
    __shared__ float gates[16][772];        // 49,408 B
    __shared__ unsigned char hA[16][264];   //  4,224 B (fp8 hidden)
    __shared__ float s_w[16][128];          //  8,192 B
    __shared__ short giLds[16 * G3];        // 24,576 B (current-step gi rows)
    __shared__ int s_len[16];
    __shared__ int s_maxlen;

    const int tid = threadIdx.x;
    const int w = tid >> 6, lane = tid & 63;
    const int dir = blockIdx.x >> 3, grp = blockIdx.x & 7;
    const int b0 = grp * 16;
    const int frow = lane & 15, fkc = (lane >> 4) * 8;   // byte offsets (fp8)
    const int colg = w * 96;
    const int r0 = (lane >> 4) * 4;
    const int dirH = dir * HDIM;

    if (tid < 16) s_len[tid] = lens[b0 + tid];
    for (int e = tid; e < 16 * 264; e += 512) ((unsigned char*)hA)[e] = 0;
    __syncthreads();
    if (tid == 0) {
        int m = 0;
        #pragma unroll
        for (int q = 0; q < 16; ++q) m = max(m, s_len[q]);
        s_maxlen = m;
    }
    for (int e = tid; e < 16 * 128; e += 512) {
        int bl = e >> 7, j = e & 127;
        int b = b0 + bl;
        int len = s_len[bl];
        s_w[bl][j] = poswt(j, beg_[b], tn_[b], len, (float)len, masks[b * LL + j]);
    }

    // ---- B fragments: 48 named i64 (96 VGPR), loaded once ----
    const unsigned char* wB = whhB + ((size_t)dir * G3 + colg + frow) * HDIM + fkc;
    LBCT(0) LBCT(1) LBCT(2) LBCT(3) LBCT(4) LBCT(5)
    KEEPCT(0) KEEPCT(1) KEEPCT(2) KEEPCT(3) KEEPCT(4) KEEPCT(5)

    const int i_idx = tid & 255;
    const int bbase = (tid >> 8) * 8;    // 8 batches per thread
    const float bhn = (dir ? gbhhb : gbhhf)[2 * HDIM + i_idx];
    const short* giD = gi + (size_t)dir * MTOT * G3;
    const unsigned char* aB = &hA[frow][fkc];
    float hv0 = 0.f, hv1 = 0.f, hv2 = 0.f, hv3 = 0.f, hv4 = 0.f, hv5 = 0.f, hv6 = 0.f, hv7 = 0.f;
    __syncthreads();
    const int maxlen = s_maxlen;

    const f32x4 zero = {0.f, 0.f, 0.f, 0.f};
    for (int l = 0; l < maxlen; ++l) {
        // ---- stage this step's gi rows into LDS (async; drained by barrier) ----
        #pragma unroll
        for (int j = 0; j < 3; ++j) {
            int flat = j * 512 + tid;            // 16B-chunk id, 0..1535
            int bl = flat / 96;
            int off16 = flat - bl * 96;
            int len = s_len[bl];
            int pos = dir ? (len - 1 - l) : l;
            if (l >= len) pos = 0;
            const char* src = (const char*)giD + ((size_t)((b0 + bl) * LL + pos) * G3 + off16 * 8) * 2;
            short* dst = &giLds[(j * 512 + (tid & ~63)) * 8];
            gload_lds16(src, dst);
        }
        // ---- MFMA: gates_pre = h @ Whh^T (fp8, fully static unrolled) ----
        f32x4 acc0 = zero, acc1 = zero, acc2 = zero, acc3 = zero, acc4 = zero, acc5 = zero;
        MM(0) MM(1) MM(2) MM(3) MM(4) MM(5) MM(6) MM(7)
        GW(0, acc0) GW(1, acc1) GW(2, acc2) GW(3, acc3) GW(4, acc4) GW(5, acc5)
        __syncthreads();   // gates + staged gi visible
        // ---- nonlinearity ----
        NQ(0, hv0) NQ(1, hv1) NQ(2, hv2) NQ(3, hv3)
        NQ(4, hv4) NQ(5, hv5) NQ(6, hv6) NQ(7, hv7)
        __syncthreads();   // hA update visible before next MFMA
    }
}

// ---------------- fused fk = ctxb @ W2^T + b2 ----------------
__global__ __launch_bounds__(256) void k_fk(const __hip_bfloat16* __restrict__ ctxb,
        const float* __restrict__ W2, const float* __restrict__ b2,
        float* __restrict__ fk) {
    int gid = blockIdx.x * 256 + threadIdx.x;  // MTOT*16
    int m = gid >> 4, kt = gid & 15;
    const short8* crow = (const short8*)((const short*)ctxb + (size_t)m * HH);
    const float* w2 = W2 + kt * HH;
    float acc = b2[kt];
    #pragma unroll 4
    for (int c = 0; c < HH / 8; ++c) {
        short8 v = crow[c];
        #pragma unroll
        for (int j = 0; j < 8; ++j)
            acc += b2f((unsigned short)v[j]) * w2[c * 8 + j];
    }
    fk[((size_t)(kt >> 2) * MTOT + m) * TT + (kt & 3)] = acc;
}

// ---------------- CRF forward/backward marginals (4 lanes per (k,b)) ----------------
__global__ __launch_bounds__(64) void k_crf(const float* __restrict__ fk,
        const float* __restrict__ trans, const int* __restrict__ lens,
        float* __restrict__ alphas, float* __restrict__ sp, float* __restrict__ spsum) {
    const int tid = blockIdx.x * 64 + threadIdx.x;   // 2048 total
    const int pid = tid >> 2;                        // 512 pairs
    const int t = tid & 3;
    const int k = pid >> 7, b = pid & 127;
    const int len = lens[b];
    const float* f = fk + ((size_t)k * MTOT + (size_t)b * LL) * TT;
    const float* tr = trans + k * 16;
    const float trC0 = tr[0 * 4 + t], trC1 = tr[1 * 4 + t], trC2 = tr[2 * 4 + t], trC3 = tr[3 * 4 + t];
    const float trR0 = tr[t * 4 + 0], trR1 = tr[t * 4 + 1], trR2 = tr[t * 4 + 2], trR3 = tr[t * 4 + 3];
    float* al = alphas + ((size_t)k * BB + b) * LL * TT;
    const int base = threadIdx.x & ~3;
    float alpha = f[t];
    al[t] = alpha;
    for (int l = 1; l < LL; ++l) {
        float a0 = __shfl(alpha, base + 0);
        float a1 = __shfl(alpha, base + 1);
        float a2 = __shfl(alpha, base + 2);
        float a3 = __shfl(alpha, base + 3);
        float v0 = a0 + trC0, v1 = a1 + trC1, v2 = a2 + trC2, v3 = a3 + trC3;
        float mx = fmaxf(fmaxf(v0, v1), fmaxf(v2, v3));
        float sum = __expf(v0 - mx) + __expf(v1 - mx) + __expf(v2 - mx) + __expf(v3 - mx);
        float nw = mx + __logf(sum) + f[l * TT + t];
        if (l < len) alpha = nw;
        al[l * TT + t] = alpha;
    }
    float beta = 0.f;
    float ssum = 0.f;
    for (int l = LL - 1; l >= 0; --l) {
        if (l < LL - 1) {
            float fb = f[(l + 1) * TT + t] + beta;
            float c0 = __shfl(fb, base + 0);
            float c1 = __shfl(fb, base + 1);
            float c2 = __shfl(fb, base + 2);
            float c3 = __shfl(fb, base + 3);
            float w0 = trR0 + c0, w1 = trR1 + c1, w2 = trR2 + c2, w3 = trR3 + c3;
            float mx = fmaxf(fmaxf(w0, w1), fmaxf(w2, w3));
            float nb = mx + __logf(__expf(w0 - mx) + __expf(w1 - mx) + __expf(w2 - mx) + __expf(w3 - mx));
            if (l + 1 < len) beta = nb;
        }
        float v = al[l * TT + t] + beta;
        float mx = fmaxf(v, __shfl_xor(v, 1));
        mx = fmaxf(mx, __shfl_xor(mx, 2));
        float p = __expf(v - mx);
        float s = p;
        s += __shfl_xor(s, 1);
        s += __shfl_xor(s, 2);
        float m1 = __shfl(p, base + 1) / s;
        float spv = (l < len) ? m1 : 0.f;
        if (t == 0) sp[((size_t)k * BB + b) * LL + l] = spv;
        ssum += spv;
    }
    if (t == 0) spsum[k * BB + b] = ssum;
}

// ---------------- pooling: sv[b, k*512+h] (bf16 ctx, vectorized) ----------------
__global__ __launch_bounds__(256) void k_pool(const __hip_bfloat16* __restrict__ ctxb,
        const float* __restrict__ sp, const float* __restrict__ spsum,
        float* __restrict__ sv) {
    __shared__ float s_sp[NKB][LL];
    __shared__ float s_inv[NKB];
    const int b = blockIdx.x;
    const int tid = threadIdx.x;
    for (int i = tid; i < NKB * LL; i += 256) {
        int k = i >> 7, l = i & 127;
        s_sp[k][l] = sp[((size_t)k * BB + b) * LL + l];
    }
    if (tid < NKB) s_inv[tid] = 1.f / spsum[tid * BB + b];
    __syncthreads();
    const int n0 = tid * 8;
    const int k = n0 >> 9, h0 = n0 & 511;
    float acc[8] = {};
    const short* cb = (const short*)ctxb;
    for (int l = 0; l < LL; ++l) {
        float spl = s_sp[k][l];
        short8 v = *(const short8*)&cb[((size_t)b * LL + l) * HH + h0];
        #pragma unroll
        for (int j = 0; j < 8; ++j)
            acc[j] += spl * b2f((unsigned short)v[j]);
    }
    float inv = s_inv[k];
    #pragma unroll
    for (int j = 0; j < 8; ++j)
        sv[(size_t)b * 2048 + n0 + j] = acc[j] * inv;
}

// ---------------- scores[b][3] = relu(sv[b]) @ lW^T + lb ----------------
__global__ __launch_bounds__(256) void k_scores(const float* __restrict__ sv,
        const float* __restrict__ lW, const float* __restrict__ lb,
        float* __restrict__ scores) {
    __shared__ float red[3][4];
    const int b = blockIdx.x;
    const int tid = threadIdx.x;
    const float* svb = sv + (size_t)b * 2048;
    float a0 = 0.f, a1 = 0.f, a2 = 0.f;
    for (int i = tid; i < 2048; i += 256) {
        float v = fmaxf(svb[i], 0.f);
        a0 += v * lW[i];
        a1 += v * lW[2048 + i];
        a2 += v * lW[4096 + i];
    }
    #pragma unroll
    for (int off = 32; off > 0; off >>= 1) {
        a0 += __shfl_down(a0, off);
        a1 += __shfl_down(a1, off);
        a2 += __shfl_down(a2, off);
    }
    const int wid = tid >> 6, lane = tid & 63;
    if (lane == 0) { red[0][wid] = a0; red[1][wid] = a1; red[2][wid] = a2; }
    __syncthreads();
    if (tid < 3) {
        scores[b * 3 + tid] = red[tid][0] + red[tid][1] + red[tid][2] + red[tid][3] + lb[tid];
    }
}

// ---------------- final: log-softmax + mean NLL (float32 out) ----------------
__global__ __launch_bounds__(128) void k_final2(const float* __restrict__ scores,
        const int* __restrict__ labels, float* __restrict__ out) {
    __shared__ float red[128];
    const int b = threadIdx.x;
    float s0 = scores[b * 3 + 0], s1 = scores[b * 3 + 1], s2 = scores[b * 3 + 2];
    float mx = fmaxf(s0, fmaxf(s1, s2));
    float lse = mx + logf(expf(s0 - mx) + expf(s1 - mx) + expf(s2 - mx));
    int lab = labels[b];
    float sc = lab == 0 ? s0 : (lab == 1 ? s1 : s2);
    red[b] = lse - sc;
    __syncthreads();
    for (int st = 64; st > 0; st >>= 1) {
        if (b < st) red[b] += red[b + st];
        __syncthreads();
    }
    if (b == 0) out[0] = red[0] * (1.f / 128.f);
}

extern "C" void kernel_launch(void* const* d_in, const int* in_sizes, int n_in,
                              void* d_out, int out_size, void* d_ws, size_t ws_size,
                              hipStream_t stream) {
    const float* sents      = (const float*)d_in[0];
    const float* mask_table = (const float*)d_in[1];
    const float* gWihf      = (const float*)d_in[2];
    const float* gWhhf      = (const float*)d_in[3];
    const float* gbihf      = (const float*)d_in[4];
    const float* gbhhf      = (const float*)d_in[5];
    const float* gWihb      = (const float*)d_in[6];
    const float* gWhhb      = (const float*)d_in[7];
    const float* gbihb      = (const float*)d_in[8];
    const float* gbhhb      = (const float*)d_in[9];
    const float* hW         = (const float*)d_in[10];
    const float* hb         = (const float*)d_in[11];
    const float* tW         = (const float*)d_in[12];
    const float* tb         = (const float*)d_in[13];
    const float* trans      = (const float*)d_in[14];
    const float* lW         = (const float*)d_in[15];
    const float* lb         = (const float*)d_in[16];
    const int*   masks      = (const int*)d_in[17];
    const int*   lens       = (const int*)d_in[18];
    const int*   labels     = (const int*)d_in[19];

    char* wsb = (char*)d_ws;
    __hip_bfloat16* gi    = (__hip_bfloat16*)(wsb + OFF_GI);
    __hip_bfloat16* ctxb  = (__hip_bfloat16*)(wsb + OFF_CTXB);
    __hip_bfloat16* wihB  = (__hip_bfloat16*)(wsb + OFF_WIHB);
    unsigned char* whhB   = (unsigned char*)(wsb + OFF_WHHB);
    float* biasAll        = (float*)(wsb + OFF_BIAS);
    float* W2             = (float*)(wsb + OFF_W2);
    float* b2             = (float*)(wsb + OFF_B2);
    int* beg              = (int*)(wsb + OFF_BEG);
    int* tn               = (int*)(wsb + OFF_TN);
    float* scores         = (float*)(wsb + OFF_SCORES);
    float* fk             = (float*)(wsb + OFF_FK);
    float* alphas         = (float*)(wsb + OFF_AL);
    float* sp             = (float*)(wsb + OFF_SP);
    float* spsum          = (float*)(wsb + OFF_SPSUM);
    float* sv             = (float*)(wsb + OFF_SV);

    hipLaunchKernelGGL(k_prep_all, dim3(NB_WIH + NB_WHH + NB_W2 + 1), dim3(256), 0, stream,
                       gWihf, gWihb, gbihf, gbihb, gbhhf, gbhhb, gWhhf, gWhhb,
                       hW, hb, tW, tb, masks, wihB, biasAll, whhB, W2, b2, beg, tn);
    hipLaunchKernelGGL(k_mfma_gi, dim3(N2 / 64, MTOT / 64), dim3(256), 0, stream,
                       sents, mask_table, masks, (const short*)wihB, biasAll, gi);
    hipLaunchKernelGGL(k_gru_mfma, dim3(16), dim3(512), 0, stream,
                       (const short*)gi, whhB, gbhhf, gbhhb, lens, masks, beg, tn, ctxb);
    hipLaunchKernelGGL(k_fk, dim3(MTOT * 16 / 256), dim3(256), 0, stream,
                       ctxb, W2, b2, fk);
    hipLaunchKernelGGL(k_crf, dim3(32), dim3(64), 0, stream, fk, trans, lens, alphas, sp, spsum);
    hipLaunchKernelGGL(k_pool, dim3(BB), dim3(256), 0, stream, ctxb, sp, spsum, sv);
    hipLaunchKernelGGL(k_scores, dim3(BB), dim3(256), 0, stream, sv, lW, lb, scores);
    hipLaunchKernelGGL(k_final2, dim3(1), dim3(128), 0, stream, scores, labels, (float*)d_out);
}